// Round 1
// baseline (238.903 us; speedup 1.0000x reference)
//
#include <hip/hip_runtime.h>

// Problem geometry (fixed by the reference):
//   probs: (B=2, C=2, D=32, H=512, W=512) fp32
//   mask : (B=2, D=32, H=512, W=512)      int32, values in {0,1,2}; 2 = ignore -> class 0
// Output: scalar fp32 = mean over all B*C*D*H*W of (probs - onehot)^2
static constexpr long long DHW       = 32LL * 512 * 512;        // 8388608 = 1<<23
static constexpr long long N_SPATIAL = 2LL * DHW;               // 16777216
static constexpr long long N_TOTAL   = 2LL * N_SPATIAL;         // 33554432 (x C)

__global__ __launch_bounds__(256) void betti_mse_reduce(const float* __restrict__ probs,
                                                        const int*   __restrict__ mask,
                                                        double*      __restrict__ acc) {
    const long long nvec   = N_SPATIAL / 4;  // float4 chunks over spatial dim
    const long long stride = (long long)gridDim.x * blockDim.x;
    float local = 0.0f;

    for (long long v = (long long)blockIdx.x * blockDim.x + threadIdx.x; v < nvec; v += stride) {
        const long long s    = v << 2;               // spatial flat index (multiple of 4)
        const long long b    = s >> 23;              // s / DHW
        const long long rest = s & (DHW - 1);        // s % DHW
        const long long base = (b << 24) + rest;     // b * C * DHW + rest  (c=0)

        const float4 p0 = *reinterpret_cast<const float4*>(probs + base);        // channel 0
        const float4 p1 = *reinterpret_cast<const float4*>(probs + base + DHW);  // channel 1
        const int4   m  = *reinterpret_cast<const int4*>(mask + s);

        // target class t in {0,1}: ignore(2)->0, so t = (m==1)
        const float t0 = (m.x == 1) ? 1.0f : 0.0f;
        const float t1 = (m.y == 1) ? 1.0f : 0.0f;
        const float t2 = (m.z == 1) ? 1.0f : 0.0f;
        const float t3 = (m.w == 1) ? 1.0f : 0.0f;

        // c=0 target = 1-t, c=1 target = t
        float d;
        d = p0.x - (1.0f - t0); local += d * d;
        d = p0.y - (1.0f - t1); local += d * d;
        d = p0.z - (1.0f - t2); local += d * d;
        d = p0.w - (1.0f - t3); local += d * d;
        d = p1.x - t0;          local += d * d;
        d = p1.y - t1;          local += d * d;
        d = p1.z - t2;          local += d * d;
        d = p1.w - t3;          local += d * d;
    }

    // wave-64 butterfly reduce
    #pragma unroll
    for (int off = 32; off > 0; off >>= 1)
        local += __shfl_down(local, off, 64);

    __shared__ float wsum[4];
    const int lane = threadIdx.x & 63;
    const int wid  = threadIdx.x >> 6;
    if (lane == 0) wsum[wid] = local;
    __syncthreads();
    if (threadIdx.x == 0) {
        const float blocksum = wsum[0] + wsum[1] + wsum[2] + wsum[3];
        atomicAdd(acc, (double)blocksum);  // device-scope f64 atomic
    }
}

__global__ void betti_finalize(const double* __restrict__ acc, float* __restrict__ out) {
    out[0] = (float)(acc[0] / (double)N_TOTAL);
}

extern "C" void kernel_launch(void* const* d_in, const int* in_sizes, int n_in,
                              void* d_out, int out_size, void* d_ws, size_t ws_size,
                              hipStream_t stream) {
    const float* probs = (const float*)d_in[0];
    const int*   mask  = (const int*)d_in[1];
    float*       out   = (float*)d_out;
    double*      acc   = (double*)d_ws;

    hipMemsetAsync(acc, 0, sizeof(double), stream);

    const int block = 256;
    const int grid  = 4096;  // 1M threads, ~4 float4 iters each over 4.19M chunks
    betti_mse_reduce<<<grid, block, 0, stream>>>(probs, mask, acc);
    betti_finalize<<<1, 1, 0, stream>>>(acc, out);
}

// Round 2
// 234.073 us; speedup vs baseline: 1.0206x; 1.0206x over previous
//
#include <hip/hip_runtime.h>

// Problem geometry (fixed by the reference):
//   probs: (B=2, C=2, D=32, H=512, W=512) fp32
//   mask : (B=2, D=32, H=512, W=512)      int32, values {0,1,2}; 2 = ignore -> class 0
// Output: scalar fp32 = mean over all B*C*D*H*W of (probs - onehot)^2
static constexpr long long DHW       = 32LL * 512 * 512;   // 8388608 = 1<<23
static constexpr long long N_SPATIAL = 2LL * DHW;          // 16777216
static constexpr long long N_TOTAL   = 2LL * N_SPATIAL;    // 33554432

static constexpr int GRID  = 2048;   // 8 blocks/CU x 4 waves = 32 waves/CU, one pass
static constexpr int BLOCK = 256;
static constexpr long long NVEC   = N_SPATIAL / 4;                 // 4194304 float4 chunks
static constexpr long long STRIDE = (long long)GRID * BLOCK;       // 524288
static_assert(NVEC == 8 * STRIDE, "exact 8 iterations per thread");

__device__ __forceinline__ float chunk_mse(const float* __restrict__ probs,
                                           const int*   __restrict__ mask,
                                           long long v) {
    const long long s    = v << 2;            // spatial flat index
    const long long b    = s >> 23;           // s / DHW
    const long long rest = s & (DHW - 1);     // s % DHW
    const long long base = (b << 24) + rest;  // b*C*DHW + rest (c=0)

    const float4 p0 = *reinterpret_cast<const float4*>(probs + base);        // c=0
    const float4 p1 = *reinterpret_cast<const float4*>(probs + base + DHW);  // c=1
    const int4   m  = *reinterpret_cast<const int4*>(mask + s);

    const float t0 = (m.x == 1) ? 1.0f : 0.0f;
    const float t1 = (m.y == 1) ? 1.0f : 0.0f;
    const float t2 = (m.z == 1) ? 1.0f : 0.0f;
    const float t3 = (m.w == 1) ? 1.0f : 0.0f;

    float acc = 0.0f, d;
    d = p0.x - (1.0f - t0); acc += d * d;
    d = p0.y - (1.0f - t1); acc += d * d;
    d = p0.z - (1.0f - t2); acc += d * d;
    d = p0.w - (1.0f - t3); acc += d * d;
    d = p1.x - t0;          acc += d * d;
    d = p1.y - t1;          acc += d * d;
    d = p1.z - t2;          acc += d * d;
    d = p1.w - t3;          acc += d * d;
    return acc;
}

__global__ __launch_bounds__(BLOCK) void betti_mse_partial(const float* __restrict__ probs,
                                                           const int*   __restrict__ mask,
                                                           double*      __restrict__ partial) {
    const long long v0 = (long long)blockIdx.x * BLOCK + threadIdx.x;
    float acc0 = 0.0f, acc1 = 0.0f;
    #pragma unroll
    for (int i = 0; i < 4; ++i) {
        // two independent chunks per unrolled step -> grouped loads, more MLP
        acc0 += chunk_mse(probs, mask, v0 + (2 * i + 0) * STRIDE);
        acc1 += chunk_mse(probs, mask, v0 + (2 * i + 1) * STRIDE);
    }
    float local = acc0 + acc1;

    #pragma unroll
    for (int off = 32; off > 0; off >>= 1)
        local += __shfl_down(local, off, 64);

    __shared__ float wsum[4];
    const int lane = threadIdx.x & 63;
    const int wid  = threadIdx.x >> 6;
    if (lane == 0) wsum[wid] = local;
    __syncthreads();
    if (threadIdx.x == 0)
        partial[blockIdx.x] = (double)(wsum[0] + wsum[1] + wsum[2] + wsum[3]);
}

__global__ __launch_bounds__(BLOCK) void betti_mse_final(const double* __restrict__ partial,
                                                         float* __restrict__ out) {
    double local = 0.0;
    #pragma unroll
    for (int k = 0; k < GRID / BLOCK; ++k)   // 8 partials per thread
        local += partial[threadIdx.x + k * BLOCK];

    #pragma unroll
    for (int off = 32; off > 0; off >>= 1)
        local += __shfl_down(local, off, 64);

    __shared__ double wsum[4];
    const int lane = threadIdx.x & 63;
    const int wid  = threadIdx.x >> 6;
    if (lane == 0) wsum[wid] = local;
    __syncthreads();
    if (threadIdx.x == 0)
        out[0] = (float)((wsum[0] + wsum[1] + wsum[2] + wsum[3]) / (double)N_TOTAL);
}

extern "C" void kernel_launch(void* const* d_in, const int* in_sizes, int n_in,
                              void* d_out, int out_size, void* d_ws, size_t ws_size,
                              hipStream_t stream) {
    const float* probs   = (const float*)d_in[0];
    const int*   mask    = (const int*)d_in[1];
    float*       out     = (float*)d_out;
    double*      partial = (double*)d_ws;   // GRID doubles = 16 KB, all overwritten

    betti_mse_partial<<<GRID, BLOCK, 0, stream>>>(probs, mask, partial);
    betti_mse_final<<<1, BLOCK, 0, stream>>>(partial, out);
}